// Round 1
// baseline (851.949 us; speedup 1.0000x reference)
//
#include <hip/hip_runtime.h>
#include <math.h>

// ---------------- kernels ----------------

__global__ void deg_kernel(const int* __restrict__ col, int* __restrict__ deg, int E) {
    int e = blockIdx.x * blockDim.x + threadIdx.x;
    if (e < E) atomicAdd(&deg[col[e]], 1);
}

__global__ void dinv_kernel(const int* __restrict__ deg, float* __restrict__ dinv, int n) {
    int i = blockIdx.x * blockDim.x + threadIdx.x;
    if (i < n) dinv[i] = 1.0f / sqrtf((float)(deg[i] + 1));  // +1 self loop
}

// out[r,c] = dinv[r] * sum_k x[r,k] * W[k,c]
template<int IC, int OC>
__global__ void gemm_scale(const float* __restrict__ x, const float* __restrict__ W,
                           const float* __restrict__ dinv, float* __restrict__ out, int n) {
    int tid = blockIdx.x * blockDim.x + threadIdx.x;
    int r = tid / OC, c = tid % OC;
    if (r >= n) return;
    const float* xr = x + (size_t)r * IC;
    float acc = 0.f;
#pragma unroll 8
    for (int k = 0; k < IC; ++k) acc = fmaf(xr[k], W[k * OC + c], acc);
    out[(size_t)r * OC + c] = acc * dinv[r];
}

// agg[col[e], f] += hs[row[e], f]   (hs already scaled by dinv[row])
template<int F>
__global__ void scatter_kernel(const int* __restrict__ row, const int* __restrict__ col,
                               const float* __restrict__ hs, float* __restrict__ agg, int E) {
    long long t = (long long)blockIdx.x * blockDim.x + threadIdx.x;
    int e = (int)(t / F), f = (int)(t % F);
    if (e >= E) return;
    int r = row[e], c = col[e];
    atomicAdd(&agg[(size_t)c * F + f], hs[(size_t)r * F + f]);
}

// out[r,f] = relu(dinv[r] * (agg[r,f] + hs[r,f]) + b[f]); optional mirror to out2 (strided)
template<int F>
__global__ void finalize_kernel(const float* __restrict__ hs, const float* __restrict__ agg,
                                const float* __restrict__ dinv, const float* __restrict__ b,
                                float* __restrict__ out, int n,
                                float* __restrict__ out2, int out2_stride) {
    long long t = (long long)blockIdx.x * blockDim.x + threadIdx.x;
    int r = (int)(t / F), f = (int)(t % F);
    if (r >= n) return;
    float v = dinv[r] * (agg[t] + hs[t]) + b[f];
    v = fmaxf(v, 0.f);
    out[t] = v;
    if (out2 != nullptr) out2[(size_t)r * out2_stride + f] = v;
}

// out[r, col0 + c] = act(sum_k x[r,k]*W[k,c] + b[c]); ACT: 0 none, 1 relu, 2 softplus
template<int IC, int OC, int ACT>
__global__ void dense_kernel(const float* __restrict__ x, const float* __restrict__ W,
                             const float* __restrict__ b, float* __restrict__ out,
                             int n, int out_stride, int col0) {
    long long tid = (long long)blockIdx.x * blockDim.x + threadIdx.x;
    int r = (int)(tid / OC), c = (int)(tid % OC);
    if (r >= n) return;
    const float* xr = x + (size_t)r * IC;
    float acc = b[c];
#pragma unroll 8
    for (int k = 0; k < IC; ++k) acc = fmaf(xr[k], W[k * OC + c], acc);
    if (ACT == 1) acc = fmaxf(acc, 0.f);
    else if (ACT == 2) acc = fmaxf(acc, 0.f) + log1pf(expf(-fabsf(acc)));  // logaddexp(x,0)
    out[(size_t)r * out_stride + col0 + c] = acc;
}

// ---------------- launch ----------------

extern "C" void kernel_launch(void* const* d_in, const int* in_sizes, int n_in,
                              void* d_out, int out_size, void* d_ws, size_t ws_size,
                              hipStream_t stream) {
    const float* raw_x = (const float*)d_in[0];
    const int*   ei    = (const int*)d_in[1];
    const float* W1 = (const float*)d_in[2];  const float* b1 = (const float*)d_in[3];
    const float* W2 = (const float*)d_in[4];  const float* b2 = (const float*)d_in[5];
    const float* Wp = (const float*)d_in[6];  const float* bp = (const float*)d_in[7];
    const float* Wd1 = (const float*)d_in[8]; const float* bd1 = (const float*)d_in[9];
    const float* Wd2 = (const float*)d_in[10]; const float* bd2 = (const float*)d_in[11];
    const float* Wd3 = (const float*)d_in[12]; const float* bd3 = (const float*)d_in[13];

    const int n = in_sizes[0] / 128;   // 50000
    const int E = in_sizes[1] / 2;     // 800000
    const int* row = ei;        // edge_index[0] = source
    const int* col = ei + E;    // edge_index[1] = target

    float* out = (float*)d_out;

    // workspace layout (floats), ~64.4 MB total
    char* ws = (char*)d_ws;
    int*   deg  = (int*)ws;
    float* dinv = (float*)(ws + (size_t)n * 4);
    float* A    = dinv + n;               // [n*64]  hs1  (later: hd2 low half)
    float* B    = A + (size_t)n * 64;     // [n*64]  agg1 -> x1 (later: hd2 high half)
    float* C    = B + (size_t)n * 64;     // [n*32]  hs2
    float* D    = C + (size_t)n * 32;     // [n*32]  agg2 -> emb
    float* Ebuf = D + (size_t)n * 32;     // [n*128] hd1
    float* Fbuf = A;                      // [n*128] hd2 (reuses A..B, contiguous)

    const int BS = 256;
    auto blocks = [](long long work, int bs) { return (unsigned)((work + bs - 1) / bs); };

    hipMemsetAsync(deg, 0, (size_t)n * 4, stream);
    hipMemsetAsync(B, 0, (size_t)n * 64 * 4, stream);
    hipMemsetAsync(D, 0, (size_t)n * 32 * 4, stream);

    deg_kernel<<<blocks(E, BS), BS, 0, stream>>>(col, deg, E);
    dinv_kernel<<<blocks(n, BS), BS, 0, stream>>>(deg, dinv, n);

    // ---- GCN layer 1: raw_x[128] -> 64 ----
    gemm_scale<128, 64><<<blocks((long long)n * 64, BS), BS, 0, stream>>>(raw_x, W1, dinv, A, n);
    scatter_kernel<64><<<blocks((long long)E * 64, BS), BS, 0, stream>>>(row, col, A, B, E);
    finalize_kernel<64><<<blocks((long long)n * 64, BS), BS, 0, stream>>>(A, B, dinv, b1, B, n, nullptr, 0);

    // ---- GCN layer 2: x1[64] -> 32 ----
    gemm_scale<64, 32><<<blocks((long long)n * 32, BS), BS, 0, stream>>>(B, W2, dinv, C, n);
    scatter_kernel<32><<<blocks((long long)E * 32, BS), BS, 0, stream>>>(row, col, C, D, E);
    // emb -> D (in place over agg2) and mirrored into out columns [0,32)
    finalize_kernel<32><<<blocks((long long)n * 32, BS), BS, 0, stream>>>(C, D, dinv, b2, D, n, out, 170);

    // ---- heads ----
    // result = emb @ Wp + bp -> out[:, 32:42]
    dense_kernel<32, 10, 0><<<blocks((long long)n * 10, BS), BS, 0, stream>>>(D, Wp, bp, out, n, 170, 32);
    // hd1 = relu(emb @ Wd1 + bd1)
    dense_kernel<32, 128, 1><<<blocks((long long)n * 128, BS), BS, 0, stream>>>(D, Wd1, bd1, Ebuf, n, 128, 0);
    // hd2 = relu(hd1 @ Wd2 + bd2)
    dense_kernel<128, 128, 1><<<blocks((long long)n * 128, BS), BS, 0, stream>>>(Ebuf, Wd2, bd2, Fbuf, n, 128, 0);
    // dec = softplus(hd2 @ Wd3 + bd3) -> out[:, 42:170]
    dense_kernel<128, 128, 2><<<blocks((long long)n * 128, BS), BS, 0, stream>>>(Fbuf, Wd3, bd3, out, n, 170, 42);
}

// Round 2
// 496.196 us; speedup vs baseline: 1.7170x; 1.7170x over previous
//
#include <hip/hip_runtime.h>
#include <math.h>

// ---------------- degree / norm ----------------

__global__ void deg_kernel(const int* __restrict__ col, int* __restrict__ deg, int E) {
    int e = blockIdx.x * blockDim.x + threadIdx.x;
    if (e < E) atomicAdd(&deg[col[e]], 1);
}

__global__ void dinv_kernel(const int* __restrict__ deg, float* __restrict__ dinv, int n) {
    int i = blockIdx.x * blockDim.x + threadIdx.x;
    if (i < n) dinv[i] = 1.0f / sqrtf((float)(deg[i] + 1));  // +1 self loop
}

// single-block exclusive scan of deg -> rowptr[n+1], cursor[n]
__global__ void scan_kernel(const int* __restrict__ deg, int* __restrict__ rowptr,
                            int* __restrict__ cursor, int n) {
    __shared__ int part[1024];
    const int tid = threadIdx.x;
    const int CH = (n + 1023) / 1024;
    const int base = tid * CH;
    int s = 0;
    for (int i = 0; i < CH; ++i) { int idx = base + i; if (idx < n) s += deg[idx]; }
    part[tid] = s;
    __syncthreads();
    // Hillis-Steele inclusive scan
    for (int off = 1; off < 1024; off <<= 1) {
        int v = part[tid];
        int w = (tid >= off) ? part[tid - off] : 0;
        __syncthreads();
        part[tid] = v + w;
        __syncthreads();
    }
    int pre = (tid > 0) ? part[tid - 1] : 0;
    for (int i = 0; i < CH; ++i) {
        int idx = base + i;
        if (idx < n) { rowptr[idx] = pre; cursor[idx] = pre; pre += deg[idx]; }
    }
    if (tid == 1023) rowptr[n] = pre;
}

// csrc[slot] = source node, grouped by target
__global__ void fill_kernel(const int* __restrict__ row, const int* __restrict__ col,
                            int* __restrict__ cursor, int* __restrict__ csrc, int E) {
    int e = blockIdx.x * blockDim.x + threadIdx.x;
    if (e < E) {
        int c = col[e];
        int slot = atomicAdd(&cursor[c], 1);
        csrc[slot] = row[e];
    }
}

// ---------------- CSR gather aggregation + finalize ----------------
// out[node, col0+f] = relu(dinv[node] * (sum_{s in N(node)} hs[s,f] + hs[node,f]) + b[f])
template<int F>
__global__ void agg_finalize(const int* __restrict__ rowptr, const int* __restrict__ csrc,
                             const float* __restrict__ hs, const float* __restrict__ dinv,
                             const float* __restrict__ b, float* __restrict__ out,
                             int n, int ostride, int col0) {
    int tid = blockIdx.x * blockDim.x + threadIdx.x;
    int node = tid / F, f = tid % F;
    if (node >= n) return;
    int beg = rowptr[node], end = rowptr[node + 1];
    float sum = 0.f;
    for (int j = beg; j < end; ++j) {
        int s = csrc[j];                       // uniform across the F-lane group
        sum += hs[(size_t)s * F + f];          // coalesced 256B/128B gather
    }
    float v = dinv[node] * (sum + hs[(size_t)node * F + f]) + b[f];
    v = fmaxf(v, 0.f);
    out[(size_t)node * ostride + col0 + f] = v;
}

// ---------------- register-tiled GEMM ----------------
// out[r, col0+c] = epilogue(sum_k x[r,k]*W[k,c])
// SCALE: multiply by dinv[r], no bias/act (GCN pre-scatter). else: +b, ACT(0/1=relu/2=softplus)
template<int K, int OC, int ACT, bool SCALE, bool XVEC, bool OVEC>
__global__ __launch_bounds__(256) void gemm_tiled(
    const float* __restrict__ x, int xstride,
    const float* __restrict__ W, const float* __restrict__ b,
    const float* __restrict__ dinv,
    float* __restrict__ out, int ostride, int col0, int n) {
    constexpr int BM = 64, BK = 32;
    constexpr int CG = OC / 8;       // col groups of 8
    constexpr int RG = 256 / CG;     // row groups
    constexpr int ROWS = BM / RG;    // rows per thread (4 / 2 / 1)
    constexpr int XPAD = 4;

    __shared__ float xT[BK][BM + XPAD];   // transposed x tile
    __shared__ float Wt[BK][OC];

    const int tid = threadIdx.x;
    const int cg = tid % CG, rg = tid / CG;
    const int c0 = cg * 8;
    const int r0 = rg * ROWS;
    const int row0 = blockIdx.x * BM;

    float acc[ROWS][8];
#pragma unroll
    for (int r = 0; r < ROWS; ++r)
#pragma unroll
        for (int c = 0; c < 8; ++c) acc[r][c] = 0.f;

    for (int k0 = 0; k0 < K; k0 += BK) {
        __syncthreads();
        // stage x (transposed into LDS)
        if (XVEC) {
#pragma unroll
            for (int i = 0; i < BM * BK / 4 / 256; ++i) {
                int e = tid + i * 256;
                int r = e / (BK / 4), q = e % (BK / 4);
                float4 v = make_float4(0.f, 0.f, 0.f, 0.f);
                if (row0 + r < n) v = *(const float4*)&x[(size_t)(row0 + r) * xstride + k0 + q * 4];
                xT[q * 4 + 0][r] = v.x; xT[q * 4 + 1][r] = v.y;
                xT[q * 4 + 2][r] = v.z; xT[q * 4 + 3][r] = v.w;
            }
        } else {
#pragma unroll
            for (int i = 0; i < BM * BK / 256; ++i) {
                int e = tid + i * 256;
                int r = e / BK, k = e % BK;
                float v = 0.f;
                if (row0 + r < n) v = x[(size_t)(row0 + r) * xstride + k0 + k];
                xT[k][r] = v;
            }
        }
        // stage W
#pragma unroll
        for (int i = 0; i < BK * OC / 4 / 256; ++i) {
            int e = tid + i * 256;
            int k = e / (OC / 4), q = e % (OC / 4);
            *(float4*)&Wt[k][q * 4] = *(const float4*)&W[(size_t)(k0 + k) * OC + q * 4];
        }
        __syncthreads();
#pragma unroll
        for (int k = 0; k < BK; ++k) {
            float xv[ROWS];
            if constexpr (ROWS == 4) {
                float4 t = *(const float4*)&xT[k][r0];
                xv[0] = t.x; xv[1] = t.y; xv[2] = t.z; xv[3] = t.w;
            } else if constexpr (ROWS == 2) {
                float2 t = *(const float2*)&xT[k][r0];
                xv[0] = t.x; xv[1] = t.y;
            } else {
                xv[0] = xT[k][r0];
            }
            float4 w0 = *(const float4*)&Wt[k][c0];
            float4 w1 = *(const float4*)&Wt[k][c0 + 4];
            float wv[8] = {w0.x, w0.y, w0.z, w0.w, w1.x, w1.y, w1.z, w1.w};
#pragma unroll
            for (int r = 0; r < ROWS; ++r)
#pragma unroll
                for (int c = 0; c < 8; ++c)
                    acc[r][c] = fmaf(xv[r], wv[c], acc[r][c]);
        }
    }
    // epilogue
#pragma unroll
    for (int r = 0; r < ROWS; ++r) {
        int gr = row0 + r0 + r;
        if (gr >= n) continue;
        float scale = SCALE ? dinv[gr] : 1.f;
        float vals[8];
#pragma unroll
        for (int c = 0; c < 8; ++c) {
            float v = acc[r][c];
            if (SCALE) v *= scale;
            else v += b[c0 + c];
            if (ACT == 1) v = fmaxf(v, 0.f);
            else if (ACT == 2) v = fmaxf(v, 0.f) + log1pf(expf(-fabsf(v)));
            vals[c] = v;
        }
        float* op = &out[(size_t)gr * ostride + col0 + c0];
        if (OVEC) {
            *(float4*)op = make_float4(vals[0], vals[1], vals[2], vals[3]);
            *(float4*)(op + 4) = make_float4(vals[4], vals[5], vals[6], vals[7]);
        } else {
#pragma unroll
            for (int c = 0; c < 8; ++c) op[c] = vals[c];
        }
    }
}

// result head: out[r, 32..42) = emb_row @ Wp + bp  (emb read from out[:,0:32))
__global__ void dense10_kernel(const float* __restrict__ out_emb, const float* __restrict__ W,
                               const float* __restrict__ b, float* __restrict__ out, int n) {
    int r = blockIdx.x * blockDim.x + threadIdx.x;
    if (r >= n) return;
    const float* xr = out_emb + (size_t)r * 170;
    float acc[10];
#pragma unroll
    for (int c = 0; c < 10; ++c) acc[c] = b[c];
#pragma unroll
    for (int k = 0; k < 32; ++k) {
        float xv = xr[k];
#pragma unroll
        for (int c = 0; c < 10; ++c) acc[c] = fmaf(xv, W[k * 10 + c], acc[c]);
    }
    float* op = &out[(size_t)r * 170 + 32];
#pragma unroll
    for (int c = 0; c < 10; ++c) op[c] = acc[c];
}

// ---------------- launch ----------------

extern "C" void kernel_launch(void* const* d_in, const int* in_sizes, int n_in,
                              void* d_out, int out_size, void* d_ws, size_t ws_size,
                              hipStream_t stream) {
    const float* raw_x = (const float*)d_in[0];
    const int*   ei    = (const int*)d_in[1];
    const float* W1 = (const float*)d_in[2];  const float* b1 = (const float*)d_in[3];
    const float* W2 = (const float*)d_in[4];  const float* b2 = (const float*)d_in[5];
    const float* Wp = (const float*)d_in[6];  const float* bp = (const float*)d_in[7];
    const float* Wd1 = (const float*)d_in[8]; const float* bd1 = (const float*)d_in[9];
    const float* Wd2 = (const float*)d_in[10]; const float* bd2 = (const float*)d_in[11];
    const float* Wd3 = (const float*)d_in[12]; const float* bd3 = (const float*)d_in[13];

    const int n = in_sizes[0] / 128;   // 50000
    const int E = in_sizes[1] / 2;     // 800000
    const int* row = ei;        // source
    const int* col = ei + E;    // target

    float* out = (float*)d_out;

    // workspace layout (~61.6 MB)
    char* ws = (char*)d_ws;
    int*   deg    = (int*)ws;                        ws += (size_t)n * 4;
    float* dinv   = (float*)ws;                      ws += (size_t)n * 4;
    int*   rowptr = (int*)ws;                        ws += (size_t)(n + 1) * 4;
    int*   cursor = (int*)ws;                        ws += (size_t)n * 4;
    int*   csrc   = (int*)ws;                        ws += (size_t)E * 4;
    float* hs1    = (float*)ws;                      // [n,64]
    float* x1     = hs1 + (size_t)n * 64;            // [n,64]
    float* hs2    = x1 + (size_t)n * 64;             // [n,32]
    float* hd1    = hs2 + (size_t)n * 32;            // [n,128]
    float* hd2    = hs1;                             // [n,128] overlays hs1+x1 (dead by then)

    const int BS = 256;
    auto blocks = [](long long work, int bs) { return (unsigned)((work + bs - 1) / bs); };

    // ---- graph structure (CSR by target) ----
    hipMemsetAsync(deg, 0, (size_t)n * 4, stream);
    deg_kernel<<<blocks(E, BS), BS, 0, stream>>>(col, deg, E);
    dinv_kernel<<<blocks(n, BS), BS, 0, stream>>>(deg, dinv, n);
    scan_kernel<<<1, 1024, 0, stream>>>(deg, rowptr, cursor, n);
    fill_kernel<<<blocks(E, BS), BS, 0, stream>>>(row, col, cursor, csrc, E);

    // ---- GCN layer 1: raw_x[128] -> 64 ----
    gemm_tiled<128, 64, 0, true, true, true><<<blocks(n, 64), 256, 0, stream>>>(
        raw_x, 128, W1, nullptr, dinv, hs1, 64, 0, n);
    agg_finalize<64><<<blocks((long long)n * 64, BS), BS, 0, stream>>>(
        rowptr, csrc, hs1, dinv, b1, x1, n, 64, 0);

    // ---- GCN layer 2: x1[64] -> 32 ----
    gemm_tiled<64, 32, 0, true, true, true><<<blocks(n, 64), 256, 0, stream>>>(
        x1, 64, W2, nullptr, dinv, hs2, 32, 0, n);
    agg_finalize<32><<<blocks((long long)n * 32, BS), BS, 0, stream>>>(
        rowptr, csrc, hs2, dinv, b2, out, n, 170, 0);   // emb -> out[:,0:32)

    // ---- heads ----
    dense10_kernel<<<blocks(n, BS), BS, 0, stream>>>(out, Wp, bp, out, n);  // out[:,32:42)
    gemm_tiled<32, 128, 1, false, false, true><<<blocks(n, 64), 256, 0, stream>>>(
        out, 170, Wd1, bd1, nullptr, hd1, 128, 0, n);   // hd1 = relu(emb@Wd1+b)
    gemm_tiled<128, 128, 1, false, true, true><<<blocks(n, 64), 256, 0, stream>>>(
        hd1, 128, Wd2, bd2, nullptr, hd2, 128, 0, n);   // hd2 = relu(hd1@Wd2+b)
    gemm_tiled<128, 128, 2, false, true, false><<<blocks(n, 64), 256, 0, stream>>>(
        hd2, 128, Wd3, bd3, nullptr, out, 170, 42, n);  // dec -> out[:,42:170)
}

// Round 3
// 316.767 us; speedup vs baseline: 2.6895x; 1.5664x over previous
//
#include <hip/hip_runtime.h>
#include <math.h>

// ---------------- degree / norm ----------------

__global__ void deg_kernel(const int* __restrict__ col, int* __restrict__ deg, int E) {
    int e = blockIdx.x * blockDim.x + threadIdx.x;
    if (e < E) atomicAdd(&deg[col[e]], 1);
}

__global__ void dinv_kernel(const int* __restrict__ deg, float* __restrict__ dinv, int n) {
    int i = blockIdx.x * blockDim.x + threadIdx.x;
    if (i < n) dinv[i] = 1.0f / sqrtf((float)(deg[i] + 1));  // +1 self loop
}

// ---------------- 3-phase scan: deg -> rowptr/cursor ----------------
// phase1: per-block (1024 elems) sums
__global__ void scan_phase1(const int* __restrict__ deg, int* __restrict__ bsum, int n) {
    __shared__ int red[256];
    int tid = threadIdx.x;
    int base = blockIdx.x * 1024 + tid * 4;
    int s = 0;
    if (base + 3 < n) { int4 v = *(const int4*)&deg[base]; s = v.x + v.y + v.z + v.w; }
    else { for (int i = 0; i < 4; ++i) if (base + i < n) s += deg[base + i]; }
    red[tid] = s; __syncthreads();
    for (int off = 128; off > 0; off >>= 1) { if (tid < off) red[tid] += red[tid + off]; __syncthreads(); }
    if (tid == 0) bsum[blockIdx.x] = red[0];
}

// phase2: one wave scans block sums (nb <= 64); also rowptr[n] = E
__global__ void scan_phase2(const int* __restrict__ bsum, int* __restrict__ bpre,
                            int nb, int* __restrict__ rowptr, int n, int E) {
    int tid = threadIdx.x;  // 64 threads
    int sv = (tid < nb) ? bsum[tid] : 0;
    int v = sv;
    for (int off = 1; off < 64; off <<= 1) {
        int w = __shfl_up(v, off);
        if (tid >= off) v += w;
    }
    if (tid < nb) bpre[tid] = v - sv;   // exclusive
    if (tid == 0) rowptr[n] = E;
}

// phase3: per-block exclusive scan + write rowptr/cursor
__global__ void scan_phase3(const int* __restrict__ deg, const int* __restrict__ bpre,
                            int* __restrict__ rowptr, int* __restrict__ cursor, int n) {
    __shared__ int tsum[256];
    int tid = threadIdx.x;
    int base = blockIdx.x * 1024 + tid * 4;
    int d[4] = {0, 0, 0, 0};
    if (base + 3 < n) { int4 v = *(const int4*)&deg[base]; d[0] = v.x; d[1] = v.y; d[2] = v.z; d[3] = v.w; }
    else { for (int i = 0; i < 4; ++i) if (base + i < n) d[i] = deg[base + i]; }
    int s = d[0] + d[1] + d[2] + d[3];
    tsum[tid] = s; __syncthreads();
    for (int off = 1; off < 256; off <<= 1) {
        int v = tsum[tid];
        int w = (tid >= off) ? tsum[tid - off] : 0;
        __syncthreads();
        tsum[tid] = v + w;
        __syncthreads();
    }
    int pre = bpre[blockIdx.x] + tsum[tid] - s;
    for (int i = 0; i < 4; ++i) {
        int idx = base + i;
        if (idx < n) { rowptr[idx] = pre; cursor[idx] = pre; pre += d[i]; }
    }
}

// csrc[slot] = source node, grouped by target
__global__ void fill_kernel(const int* __restrict__ row, const int* __restrict__ col,
                            int* __restrict__ cursor, int* __restrict__ csrc, int E) {
    int e = blockIdx.x * blockDim.x + threadIdx.x;
    if (e < E) {
        int c = col[e];
        int slot = atomicAdd(&cursor[c], 1);
        csrc[slot] = row[e];
    }
}

// ---------------- CSR gather aggregation + finalize ----------------
// F/4 lanes per node, float4 gathers.
// out[node, col0+f] = relu(dinv[node] * (sum_{s in N(node)} hs[s,f] + hs[node,f]) + b[f])
template<int F>
__global__ void agg_finalize(const int* __restrict__ rowptr, const int* __restrict__ csrc,
                             const float* __restrict__ hs, const float* __restrict__ dinv,
                             const float* __restrict__ b, float* __restrict__ out,
                             int n, int ostride, int col0) {
    constexpr int L = F / 4;                 // lanes per node
    int tid = blockIdx.x * blockDim.x + threadIdx.x;
    int node = tid / L, lane = tid % L;
    if (node >= n) return;
    int f0 = lane * 4;
    int beg = rowptr[node], end = rowptr[node + 1];
    float4 sum = make_float4(0.f, 0.f, 0.f, 0.f);
    for (int j = beg; j < end; ++j) {
        int s = csrc[j];                     // uniform across the L-lane group
        float4 v = *(const float4*)&hs[(size_t)s * F + f0];
        sum.x += v.x; sum.y += v.y; sum.z += v.z; sum.w += v.w;
    }
    float4 self = *(const float4*)&hs[(size_t)node * F + f0];
    float di = dinv[node];
    float* op = &out[(size_t)node * ostride + col0 + f0];
    op[0] = fmaxf(di * (sum.x + self.x) + b[f0 + 0], 0.f);
    op[1] = fmaxf(di * (sum.y + self.y) + b[f0 + 1], 0.f);
    op[2] = fmaxf(di * (sum.z + self.z) + b[f0 + 2], 0.f);
    op[3] = fmaxf(di * (sum.w + self.w) + b[f0 + 3], 0.f);
}

// ---------------- register-tiled GEMM ----------------
template<int K, int OC, int ACT, bool SCALE, bool XVEC, bool OVEC>
__global__ __launch_bounds__(256) void gemm_tiled(
    const float* __restrict__ x, int xstride,
    const float* __restrict__ W, const float* __restrict__ b,
    const float* __restrict__ dinv,
    float* __restrict__ out, int ostride, int col0, int n) {
    constexpr int BM = 64, BK = 32;
    constexpr int CG = OC / 8;       // col groups of 8
    constexpr int RG = 256 / CG;     // row groups
    constexpr int ROWS = BM / RG;    // rows per thread (4 / 2 / 1)
    constexpr int XPAD = 4;

    __shared__ float xT[BK][BM + XPAD];   // transposed x tile
    __shared__ float Wt[BK][OC];

    const int tid = threadIdx.x;
    const int cg = tid % CG, rg = tid / CG;
    const int c0 = cg * 8;
    const int r0 = rg * ROWS;
    const int row0 = blockIdx.x * BM;

    float acc[ROWS][8];
#pragma unroll
    for (int r = 0; r < ROWS; ++r)
#pragma unroll
        for (int c = 0; c < 8; ++c) acc[r][c] = 0.f;

    for (int k0 = 0; k0 < K; k0 += BK) {
        __syncthreads();
        if (XVEC) {
#pragma unroll
            for (int i = 0; i < BM * BK / 4 / 256; ++i) {
                int e = tid + i * 256;
                int r = e / (BK / 4), q = e % (BK / 4);
                float4 v = make_float4(0.f, 0.f, 0.f, 0.f);
                if (row0 + r < n) v = *(const float4*)&x[(size_t)(row0 + r) * xstride + k0 + q * 4];
                xT[q * 4 + 0][r] = v.x; xT[q * 4 + 1][r] = v.y;
                xT[q * 4 + 2][r] = v.z; xT[q * 4 + 3][r] = v.w;
            }
        } else {
#pragma unroll
            for (int i = 0; i < BM * BK / 256; ++i) {
                int e = tid + i * 256;
                int r = e / BK, k = e % BK;
                float v = 0.f;
                if (row0 + r < n) v = x[(size_t)(row0 + r) * xstride + k0 + k];
                xT[k][r] = v;
            }
        }
#pragma unroll
        for (int i = 0; i < BK * OC / 4 / 256; ++i) {
            int e = tid + i * 256;
            int k = e / (OC / 4), q = e % (OC / 4);
            *(float4*)&Wt[k][q * 4] = *(const float4*)&W[(size_t)(k0 + k) * OC + q * 4];
        }
        __syncthreads();
#pragma unroll
        for (int k = 0; k < BK; ++k) {
            float xv[ROWS];
            if constexpr (ROWS == 4) {
                float4 t = *(const float4*)&xT[k][r0];
                xv[0] = t.x; xv[1] = t.y; xv[2] = t.z; xv[3] = t.w;
            } else if constexpr (ROWS == 2) {
                float2 t = *(const float2*)&xT[k][r0];
                xv[0] = t.x; xv[1] = t.y;
            } else {
                xv[0] = xT[k][r0];
            }
            float4 w0 = *(const float4*)&Wt[k][c0];
            float4 w1 = *(const float4*)&Wt[k][c0 + 4];
            float wv[8] = {w0.x, w0.y, w0.z, w0.w, w1.x, w1.y, w1.z, w1.w};
#pragma unroll
            for (int r = 0; r < ROWS; ++r)
#pragma unroll
                for (int c = 0; c < 8; ++c)
                    acc[r][c] = fmaf(xv[r], wv[c], acc[r][c]);
        }
    }
#pragma unroll
    for (int r = 0; r < ROWS; ++r) {
        int gr = row0 + r0 + r;
        if (gr >= n) continue;
        float scale = SCALE ? dinv[gr] : 1.f;
        float vals[8];
#pragma unroll
        for (int c = 0; c < 8; ++c) {
            float v = acc[r][c];
            if (SCALE) v *= scale;
            else v += b[c0 + c];
            if (ACT == 1) v = fmaxf(v, 0.f);
            else if (ACT == 2) v = fmaxf(v, 0.f) + log1pf(expf(-fabsf(v)));
            vals[c] = v;
        }
        float* op = &out[(size_t)gr * ostride + col0 + c0];
        if (OVEC) {
            *(float4*)op = make_float4(vals[0], vals[1], vals[2], vals[3]);
            *(float4*)(op + 4) = make_float4(vals[4], vals[5], vals[6], vals[7]);
        } else {
#pragma unroll
            for (int c = 0; c < 8; ++c) op[c] = vals[c];
        }
    }
}

// result head: out[r, 32..42) = emb_row @ Wp + bp  (emb read from out[:,0:32))
__global__ void dense10_kernel(const float* __restrict__ out_emb, const float* __restrict__ W,
                               const float* __restrict__ b, float* __restrict__ out, int n) {
    int r = blockIdx.x * blockDim.x + threadIdx.x;
    if (r >= n) return;
    const float* xr = out_emb + (size_t)r * 170;
    float acc[10];
#pragma unroll
    for (int c = 0; c < 10; ++c) acc[c] = b[c];
#pragma unroll
    for (int k = 0; k < 32; ++k) {
        float xv = xr[k];
#pragma unroll
        for (int c = 0; c < 10; ++c) acc[c] = fmaf(xv, W[k * 10 + c], acc[c]);
    }
    float* op = &out[(size_t)r * 170 + 32];
#pragma unroll
    for (int c = 0; c < 10; ++c) op[c] = acc[c];
}

// ---------------- launch ----------------

extern "C" void kernel_launch(void* const* d_in, const int* in_sizes, int n_in,
                              void* d_out, int out_size, void* d_ws, size_t ws_size,
                              hipStream_t stream) {
    const float* raw_x = (const float*)d_in[0];
    const int*   ei    = (const int*)d_in[1];
    const float* W1 = (const float*)d_in[2];  const float* b1 = (const float*)d_in[3];
    const float* W2 = (const float*)d_in[4];  const float* b2 = (const float*)d_in[5];
    const float* Wp = (const float*)d_in[6];  const float* bp = (const float*)d_in[7];
    const float* Wd1 = (const float*)d_in[8]; const float* bd1 = (const float*)d_in[9];
    const float* Wd2 = (const float*)d_in[10]; const float* bd2 = (const float*)d_in[11];
    const float* Wd3 = (const float*)d_in[12]; const float* bd3 = (const float*)d_in[13];

    const int n = in_sizes[0] / 128;   // 50000
    const int E = in_sizes[1] / 2;     // 800000
    const int* row = ei;        // source
    const int* col = ei + E;    // target

    float* out = (float*)d_out;

    // workspace layout (~62 MB)
    char* ws = (char*)d_ws;
    int*   deg    = (int*)ws;                        ws += (size_t)n * 4;
    float* dinv   = (float*)ws;                      ws += (size_t)n * 4;
    int*   rowptr = (int*)ws;                        ws += (size_t)(n + 4) * 4;
    int*   cursor = (int*)ws;                        ws += (size_t)n * 4;
    int*   bsum   = (int*)ws;                        ws += 64 * 4;
    int*   bpre   = (int*)ws;                        ws += 64 * 4;
    int*   csrc   = (int*)ws;                        ws += (size_t)E * 4;
    float* hs1    = (float*)ws;                      // [n,64]
    float* x1     = hs1 + (size_t)n * 64;            // [n,64]
    float* hs2    = x1 + (size_t)n * 64;             // [n,32]
    float* hd1    = hs2 + (size_t)n * 32;            // [n,128]
    float* hd2    = hs1;                             // [n,128] overlays hs1+x1 (dead by then)

    const int BS = 256;
    auto blocks = [](long long work, int bs) { return (unsigned)((work + bs - 1) / bs); };
    const int nb = (n + 1023) / 1024;                // scan blocks (49)

    // ---- graph structure (CSR by target) ----
    hipMemsetAsync(deg, 0, (size_t)n * 4, stream);
    deg_kernel<<<blocks(E, BS), BS, 0, stream>>>(col, deg, E);
    dinv_kernel<<<blocks(n, BS), BS, 0, stream>>>(deg, dinv, n);
    scan_phase1<<<nb, 256, 0, stream>>>(deg, bsum, n);
    scan_phase2<<<1, 64, 0, stream>>>(bsum, bpre, nb, rowptr, n, E);
    scan_phase3<<<nb, 256, 0, stream>>>(deg, bpre, rowptr, cursor, n);
    fill_kernel<<<blocks(E, BS), BS, 0, stream>>>(row, col, cursor, csrc, E);

    // ---- GCN layer 1: raw_x[128] -> 64 ----
    gemm_tiled<128, 64, 0, true, true, true><<<blocks(n, 64), 256, 0, stream>>>(
        raw_x, 128, W1, nullptr, dinv, hs1, 64, 0, n);
    agg_finalize<64><<<blocks((long long)n * 16, BS), BS, 0, stream>>>(
        rowptr, csrc, hs1, dinv, b1, x1, n, 64, 0);

    // ---- GCN layer 2: x1[64] -> 32 ----
    gemm_tiled<64, 32, 0, true, true, true><<<blocks(n, 64), 256, 0, stream>>>(
        x1, 64, W2, nullptr, dinv, hs2, 32, 0, n);
    agg_finalize<32><<<blocks((long long)n * 8, BS), BS, 0, stream>>>(
        rowptr, csrc, hs2, dinv, b2, out, n, 170, 0);   // emb -> out[:,0:32)

    // ---- heads ----
    dense10_kernel<<<blocks(n, BS), BS, 0, stream>>>(out, Wp, bp, out, n);  // out[:,32:42)
    gemm_tiled<32, 128, 1, false, false, true><<<blocks(n, 64), 256, 0, stream>>>(
        out, 170, Wd1, bd1, nullptr, hd1, 128, 0, n);   // hd1 = relu(emb@Wd1+b)
    gemm_tiled<128, 128, 1, false, true, true><<<blocks(n, 64), 256, 0, stream>>>(
        hd1, 128, Wd2, bd2, nullptr, hd2, 128, 0, n);   // hd2 = relu(hd1@Wd2+b)
    gemm_tiled<128, 128, 2, false, true, false><<<blocks(n, 64), 256, 0, stream>>>(
        hd2, 128, Wd3, bd3, nullptr, out, 170, 42, n);  // dec -> out[:,42:170)
}